// Round 3
// baseline (859.227 us; speedup 1.0000x reference)
//
#include <hip/hip_runtime.h>

#define BIGF 100000000.0f
#define LOG2E 1.4426950408889634f
#define LN2f 0.6931471805599453f
constexpr int BATCH = 64;
constexpr int T = 512;     // N == M == 512
constexpr int DIMS = 64;

#if __has_builtin(__builtin_amdgcn_exp2f)
#define EXP2F(x) __builtin_amdgcn_exp2f(x)
#else
#define EXP2F(x) __expf((x) * LN2f)
#endif
#if __has_builtin(__builtin_amdgcn_logf)
#define LOG2F(x) __builtin_amdgcn_logf(x)
#else
#define LOG2F(x) (__logf(x) * LOG2E)
#endif

// ---------------------------------------------------------------------------
// Kernel A: pairwise squared distances, written in DIAGONAL-PACKED layout,
// pre-scaled by log2(e).  Packed offset of diagonal d (d = i + j, 1-indexed
// i,j in [1,T]):  d<=T+1: off=(d-2)(d-1)/2, lo=1;  else off=T*T-(2T+1-d)(2T+2-d)/2,
// lo=d-T.  Cell (i, d-i) stored at off + (i - lo).  Total exactly T*T floats.
// ---------------------------------------------------------------------------
__global__ __launch_bounds__(256) void pairdist_diag_kernel(
    const float* __restrict__ x, const float* __restrict__ y,
    float* __restrict__ D) {
  int bid = blockIdx.x;
  int b = bid >> 6;          // 64 tiles per batch
  int tile = bid & 63;
  int n0 = (tile >> 3) << 6; // row tile origin
  int m0 = (tile & 7) << 6;  // col tile origin

  __shared__ float xs[64][65];
  __shared__ float ys[64][65];
  __shared__ float stage[64][66];  // stride 66: diag read r*66+(t-r) -> bank step 65&31=1, conflict-free
  __shared__ float x2s[64], y2s[64];

  const float* xb = x + ((size_t)b * T + n0) * DIMS;
  const float* yb = y + ((size_t)b * T + m0) * DIMS;
  int tid = threadIdx.x;

  for (int e = tid; e < 64 * 64; e += 256) {
    int r = e >> 6, c = e & 63;
    xs[r][c] = xb[(size_t)r * DIMS + c];
    ys[r][c] = yb[(size_t)r * DIMS + c];
  }
  __syncthreads();

  if (tid < 64) {
    float s = 0.f;
    #pragma unroll
    for (int k = 0; k < 64; ++k) { float v = xs[tid][k]; s += v * v; }
    x2s[tid] = s;
  } else if (tid < 128) {
    int r = tid - 64;
    float s = 0.f;
    #pragma unroll
    for (int k = 0; k < 64; ++k) { float v = ys[r][k]; s += v * v; }
    y2s[r] = s;
  }
  __syncthreads();

  int tr = tid >> 4, tc = tid & 15;
  int r0 = tr * 4, c0 = tc * 4;
  float acc[4][4] = {};
  #pragma unroll 8
  for (int k = 0; k < 64; ++k) {
    float a0 = xs[r0 + 0][k], a1 = xs[r0 + 1][k];
    float a2 = xs[r0 + 2][k], a3 = xs[r0 + 3][k];
    float b0 = ys[c0 + 0][k], b1 = ys[c0 + 1][k];
    float b2 = ys[c0 + 2][k], b3 = ys[c0 + 3][k];
    acc[0][0] += a0 * b0; acc[0][1] += a0 * b1; acc[0][2] += a0 * b2; acc[0][3] += a0 * b3;
    acc[1][0] += a1 * b0; acc[1][1] += a1 * b1; acc[1][2] += a1 * b2; acc[1][3] += a1 * b3;
    acc[2][0] += a2 * b0; acc[2][1] += a2 * b1; acc[2][2] += a2 * b2; acc[2][3] += a2 * b3;
    acc[3][0] += a3 * b0; acc[3][1] += a3 * b1; acc[3][2] += a3 * b2; acc[3][3] += a3 * b3;
  }

  #pragma unroll
  for (int r = 0; r < 4; ++r) {
    float xn = x2s[r0 + r];
    #pragma unroll
    for (int c = 0; c < 4; ++c)
      stage[r0 + r][c0 + c] = (xn + y2s[c0 + c] - 2.f * acc[r][c]) * LOG2E;
  }
  __syncthreads();

  // packed-diagonal writeout: 4 tile-diagonals per pass, lanes cover a diagonal
  float* Dp = D + (size_t)b * (T * T);
  int sub = tid >> 6, p = tid & 63;
  #pragma unroll 1
  for (int t4 = 0; t4 < 128; t4 += 4) {
    int t = t4 + sub;                   // tile-diagonal 0..126 (127 skipped)
    int rlo = (t > 63) ? t - 63 : 0;
    int rhi = (t < 63) ? t : 63;
    int r = rlo + p;
    if (t <= 126 && r <= rhi) {
      int c = t - r;
      int i = n0 + r + 1;
      int d = n0 + m0 + t + 2;
      int lo = (d <= T + 1) ? 1 : d - T;
      int off = (d <= T + 1) ? (((d - 2) * (d - 1)) >> 1)
                             : (T * T - (((2 * T + 1 - d) * (2 * T + 2 - d)) >> 1));
      Dp[off + (i - lo)] = stage[r][c];
    }
  }
}

// ---------------------------------------------------------------------------
// Kernel B: single-wave register DP.  Lane l owns rows i = 64k + l + 1,
// k = 0..7 (strided), values for 3 consecutive diagonals in cyclic register
// arrays.  Up/diag deps come from lane l-1 via ds_bpermute rotation; lane 0
// of slot k takes the previous slot's rotated value (row 64k).  No LDS, no
// barriers -> cost prefetch (3 diagonals ahead) is never drained.
// ---------------------------------------------------------------------------
#define LOADDIAG(CARR, dp_)                                                   \
  if ((dp_) <= 2 * T) {                                                       \
    const int lop  = ((dp_) <= T + 1) ? 1 : (dp_) - T;                        \
    const int hip2 = ((dp_) - 1 < T) ? (dp_) - 1 : T;                         \
    const int klop = (lop - 1) >> 6;                                          \
    const int khip = (hip2 - 1) >> 6;                                         \
    const int offp = ((dp_) <= T + 1)                                         \
        ? ((((dp_) - 2) * ((dp_) - 1)) >> 1)                                  \
        : (T * T - (((2 * T + 1 - (dp_)) * (2 * T + 2 - (dp_))) >> 1));       \
    const float* Dr = Db + offp - lop;                                        \
    _Pragma("unroll")                                                         \
    for (int k = 0; k < 8; ++k)                                               \
      if (k >= klop && k <= khip) CARR[k] = Dr[(k << 6) + lane + 1];          \
  }

#define STEP(dd_, RP2, RP1, ROUT, CARR)                                       \
  {                                                                           \
    const int dd  = (dd_);                                                    \
    const int lo  = (dd <= T + 1) ? 1 : dd - T;                               \
    const int hi  = (dd - 1 < T) ? dd - 1 : T;                                \
    const int klo = (lo - 1) >> 6;                                            \
    const int khi = (hi - 1) >> 6;                                            \
    const int krot = (klo > 0) ? klo - 1 : 0;                                 \
    float rot1[8], rot2[8];                                                   \
    _Pragma("unroll")                                                         \
    for (int k = 0; k < 8; ++k)                                               \
      if (k >= krot && k <= khi) {                                            \
        rot1[k] = __int_as_float(__builtin_amdgcn_ds_bpermute(                \
            rot_addr, __float_as_int(RP1[k])));                               \
        rot2[k] = __int_as_float(__builtin_amdgcn_ds_bpermute(                \
            rot_addr, __float_as_int(RP2[k])));                               \
      }                                                                       \
    const float dzero = (dd == 2) ? 0.0f : BIGF;                              \
    _Pragma("unroll")                                                         \
    for (int k = 0; k < 8; ++k)                                               \
      if (k >= klo && k <= khi) {                                             \
        const int i = (k << 6) + lane + 1;                                    \
        float up, dg;                                                         \
        if (k == 0) {                                                         \
          up = (lane == 0) ? BIGF : rot1[0];                                  \
          dg = (lane == 0) ? dzero : rot2[0];                                 \
        } else {                                                              \
          up = (lane == 0) ? rot1[k - 1] : rot1[k];                           \
          dg = (lane == 0) ? rot2[k - 1] : rot2[k];                           \
        }                                                                     \
        const float lf = RP1[k];                                              \
        const float mn = fminf(fminf(up, lf), dg);                            \
        const float md = __builtin_amdgcn_fmed3f(up, lf, dg);                 \
        const float mx = fmaxf(fmaxf(up, lf), dg);                            \
        const float s  = 1.0f + EXP2F(mn - md) + EXP2F(mn - mx);              \
        const float val = CARR[k] + mn - LOG2F(s);                            \
        const unsigned ju = (unsigned)(dd - i - 1);                           \
        ROUT[k] = (ju < (unsigned)T) ? val : BIGF;                            \
      }                                                                       \
    LOADDIAG(CARR, dd + 3)                                                    \
  }

__global__ __launch_bounds__(64) void dp_diag_kernel(const float* __restrict__ D,
                                                     float* __restrict__ out) {
  const int b = blockIdx.x;
  const int lane = threadIdx.x;
  const float* __restrict__ Db = D + (size_t)b * (T * T);
  const int rot_addr = ((lane + 63) & 63) << 2;  // byte addr of lane-1 (mod 64)

  float A[8], Bv[8], C[8];
  float cA[8], cB[8], cC[8];
  #pragma unroll
  for (int k = 0; k < 8; ++k) {
    A[k] = BIGF; Bv[k] = BIGF; C[k] = BIGF;
    cA[k] = 0.f; cB[k] = 0.f; cC[k] = 0.f;
  }

  LOADDIAG(cA, 2)
  LOADDIAG(cB, 3)
  LOADDIAG(cC, 4)

  // A = diag 0 (all BIG; R[0][0]=0 handled by the k==0/lane==0 override),
  // Bv = diag 1 (all BIG).  1023 diagonals = 341 x 3 exactly.
  #pragma unroll 1
  for (int d0 = 2; d0 <= 2 * T; d0 += 3) {
    STEP(d0,     A,  Bv, C,  cA)
    STEP(d0 + 1, Bv, C,  A,  cB)
    STEP(d0 + 2, C,  A,  Bv, cC)
  }

  // diag 1024 landed in Bv; R'(512,512) is slot 7, lane 63.  Unscale by ln2.
  if (lane == 63) atomicAdd(out, Bv[7] * (LN2f / BATCH));
}

// ---------------------------------------------------------------------------
// Fallback (ws too small): fused on-the-fly DP (round-2 version, known good).
// ---------------------------------------------------------------------------
__global__ __launch_bounds__(512) void dp_onfly_kernel(
    const float* __restrict__ x, const float* __restrict__ y,
    float* __restrict__ out) {
  int b = blockIdx.x;
  int tid = threadIdx.x;
  int i = tid + 1;

  __shared__ float ys[T][DIMS + 1];
  __shared__ float y2s[T];
  __shared__ float rbuf[3][T + 1];

  const float* yb = y + (size_t)b * T * DIMS;
  for (int e = tid; e < T * DIMS; e += 512) {
    int r = e >> 6, c = e & 63;
    ys[r][c] = yb[e];
  }
  for (int e = tid; e < 3 * (T + 1); e += 512) ((float*)rbuf)[e] = BIGF;
  __syncthreads();
  if (tid == 0) rbuf[0][0] = 0.f;
  {
    float s = 0.f;
    #pragma unroll
    for (int k = 0; k < DIMS; ++k) { float v = ys[tid][k]; s += v * v; }
    y2s[tid] = s;
  }

  float xr[DIMS];
  float x2 = 0.f;
  const float* xb = x + ((size_t)b * T + (i - 1)) * DIMS;
  #pragma unroll
  for (int k = 0; k < DIMS; ++k) { xr[k] = xb[k]; x2 += xr[k] * xr[k]; }
  __syncthreads();

  float* rp2 = rbuf[0];
  float* rp1 = rbuf[1];
  float* rc  = rbuf[2];

  float val = BIGF;
  for (int d = 2; d <= 2 * T; ++d) {
    int j = d - i;
    bool valid = (j >= 1) && (j <= T);
    float cost = 0.f;
    if (valid) {
      float dot = 0.f;
      #pragma unroll
      for (int k = 0; k < DIMS; ++k) dot += xr[k] * ys[j - 1][k];
      cost = x2 + y2s[j - 1] - 2.f * dot;
    }
    float a = rp1[i - 1];
    float bb = rp1[i];
    float c = rp2[i - 1];
    float m = fminf(fminf(a, bb), c);
    float s = __expf(m - a) + __expf(m - bb) + __expf(m - c);
    val = valid ? (cost + m - __logf(s)) : BIGF;
    rc[i] = val;
    if (tid == 0) rc[0] = BIGF;
    __syncthreads();
    float* tmp = rp2; rp2 = rp1; rp1 = rc; rc = tmp;
  }

  if (tid == T - 1) atomicAdd(out, val * (1.0f / BATCH));
}

extern "C" void kernel_launch(void* const* d_in, const int* in_sizes, int n_in,
                              void* d_out, int out_size, void* d_ws, size_t ws_size,
                              hipStream_t stream) {
  const float* x = (const float*)d_in[0];   // inputs  (B,T,D)
  const float* y = (const float*)d_in[1];   // targets (B,T,D)
  float* out = (float*)d_out;

  hipMemsetAsync(d_out, 0, sizeof(float), stream);

  size_t needD = (size_t)BATCH * T * T * sizeof(float);  // 64 MiB
  if (ws_size >= needD) {
    float* Dw = (float*)d_ws;
    pairdist_diag_kernel<<<BATCH * 64, 256, 0, stream>>>(x, y, Dw);
    dp_diag_kernel<<<BATCH, 64, 0, stream>>>(Dw, out);
  } else {
    dp_onfly_kernel<<<BATCH, 512, 0, stream>>>(x, y, out);
  }
}

// Round 4
// 744.224 us; speedup vs baseline: 1.1545x; 1.1545x over previous
//
#include <hip/hip_runtime.h>

#define BIGF 100000000.0f
#define LOG2E 1.4426950408889634f
#define LN2f 0.6931471805599453f
constexpr int BATCH = 64;
constexpr int T = 512;     // N == M == 512
constexpr int DIMS = 64;

#if __has_builtin(__builtin_amdgcn_exp2f)
#define EXP2F(x) __builtin_amdgcn_exp2f(x)
#else
#define EXP2F(x) __expf((x) * LN2f)
#endif
#if __has_builtin(__builtin_amdgcn_logf)
#define LOG2F(x) __builtin_amdgcn_logf(x)
#else
#define LOG2F(x) (__logf(x) * LOG2E)
#endif

// lane l <- lane l-1, lane 0 <- lane 63 (full-wave rotate right by 1).
// DPP ctrl 0x13C = wave_ror:1 (gfx9 lineage). VALU-speed, replaces the
// ~120-cyc ds_bpermute in the per-diagonal serial chain.
#if __has_builtin(__builtin_amdgcn_update_dpp)
#define ROTL1(x) __int_as_float(__builtin_amdgcn_update_dpp(               \
    0, __float_as_int(x), 0x13C, 0xF, 0xF, 1))
#else
#define ROTL1(x) __int_as_float(__builtin_amdgcn_ds_bpermute(              \
    rot_addr, __float_as_int(x)))
#endif

// ---------------------------------------------------------------------------
// Kernel A: pairwise squared distances, written DIAGONAL-PACKED, pre-scaled
// by log2(e).  Diagonal d (d = i + j, i,j in [1,T]):
//   d <= T+1: lo = 1,   off = (d-2)(d-1)/2
//   else:     lo = d-T, off = T*T - (2T+1-d)(2T+2-d)/2
// Cell (i, d-i) stored at off + (i - lo).  Total exactly T*T floats.
// ---------------------------------------------------------------------------
__global__ __launch_bounds__(256) void pairdist_diag_kernel(
    const float* __restrict__ x, const float* __restrict__ y,
    float* __restrict__ D) {
  int bid = blockIdx.x;
  int b = bid >> 6;          // 64 tiles per batch
  int tile = bid & 63;
  int n0 = (tile >> 3) << 6; // row tile origin
  int m0 = (tile & 7) << 6;  // col tile origin

  __shared__ float xs[64][65];
  __shared__ float ys[64][65];
  __shared__ float stage[64][66];  // diag read addr = 65r + t -> bank (r+t)&31, conflict-free
  __shared__ float x2s[64], y2s[64];

  const float* xb = x + ((size_t)b * T + n0) * DIMS;
  const float* yb = y + ((size_t)b * T + m0) * DIMS;
  int tid = threadIdx.x;

  for (int e = tid; e < 64 * 64; e += 256) {
    int r = e >> 6, c = e & 63;
    xs[r][c] = xb[(size_t)r * DIMS + c];
    ys[r][c] = yb[(size_t)r * DIMS + c];
  }
  __syncthreads();

  if (tid < 64) {
    float s = 0.f;
    #pragma unroll
    for (int k = 0; k < 64; ++k) { float v = xs[tid][k]; s += v * v; }
    x2s[tid] = s;
  } else if (tid < 128) {
    int r = tid - 64;
    float s = 0.f;
    #pragma unroll
    for (int k = 0; k < 64; ++k) { float v = ys[r][k]; s += v * v; }
    y2s[r] = s;
  }
  __syncthreads();

  int tr = tid >> 4, tc = tid & 15;
  int r0 = tr * 4, c0 = tc * 4;
  float acc[4][4] = {};
  #pragma unroll 8
  for (int k = 0; k < 64; ++k) {
    float a0 = xs[r0 + 0][k], a1 = xs[r0 + 1][k];
    float a2 = xs[r0 + 2][k], a3 = xs[r0 + 3][k];
    float b0 = ys[c0 + 0][k], b1 = ys[c0 + 1][k];
    float b2 = ys[c0 + 2][k], b3 = ys[c0 + 3][k];
    acc[0][0] += a0 * b0; acc[0][1] += a0 * b1; acc[0][2] += a0 * b2; acc[0][3] += a0 * b3;
    acc[1][0] += a1 * b0; acc[1][1] += a1 * b1; acc[1][2] += a1 * b2; acc[1][3] += a1 * b3;
    acc[2][0] += a2 * b0; acc[2][1] += a2 * b1; acc[2][2] += a2 * b2; acc[2][3] += a2 * b3;
    acc[3][0] += a3 * b0; acc[3][1] += a3 * b1; acc[3][2] += a3 * b2; acc[3][3] += a3 * b3;
  }

  #pragma unroll
  for (int r = 0; r < 4; ++r) {
    float xn = x2s[r0 + r];
    #pragma unroll
    for (int c = 0; c < 4; ++c)
      stage[r0 + r][c0 + c] = (xn + y2s[c0 + c] - 2.f * acc[r][c]) * LOG2E;
  }
  __syncthreads();

  // packed writeout: wave `sub` handles tile-diagonal t = sub + 4j.
  // sub is forced scalar -> all t/d/lo/off math lands in SALU.
  float* Dp = D + (size_t)b * (T * T);
  int p = tid & 63;
  int sub = __builtin_amdgcn_readfirstlane(tid >> 6);
  int ldsoff = 65 * p;
  #pragma unroll 1
  for (int t = sub; t <= 126; t += 4) {
    int rlo = (t > 63) ? t - 63 : 0;
    int rhi = (t < 63) ? t : 63;
    int d = n0 + m0 + t + 2;
    int lo = (d <= T + 1) ? 1 : d - T;
    int off = (d <= T + 1) ? (((d - 2) * (d - 1)) >> 1)
                           : (T * T - (((2 * T + 1 - d) * (2 * T + 2 - d)) >> 1));
    int r = rlo + p;
    if (r <= rhi) {
      float v = ((const float*)stage)[ldsoff + 65 * rlo + t];  // stage[r][t-r]
      Dp[off + (n0 + r + 1 - lo)] = v;
    }
  }
}

// ---------------------------------------------------------------------------
// Kernel B: single-wave register DP.  Lane l owns rows i = 64k + l + 1
// (k = 0..7).  3 cyclic diagonal registers, DPP wave_ror:1 for the lane-1
// neighbor, 6-deep cost prefetch (coalesced 256B per slot) so HBM latency
// hides without any barrier.  launch_bounds(64,1): full VGPR file, no spill.
// ---------------------------------------------------------------------------
#define LOADDIAG(CARR, dp_)                                                   \
  if ((dp_) <= 2 * T) {                                                       \
    const int lop  = ((dp_) <= T + 1) ? 1 : (dp_) - T;                        \
    const int hip2 = ((dp_) - 1 < T) ? (dp_) - 1 : T;                         \
    const int klop = (lop - 1) >> 6;                                          \
    const int khip = (hip2 - 1) >> 6;                                         \
    const int offp = ((dp_) <= T + 1)                                         \
        ? ((((dp_) - 2) * ((dp_) - 1)) >> 1)                                  \
        : (T * T - (((2 * T + 1 - (dp_)) * (2 * T + 2 - (dp_))) >> 1));       \
    const float* Dr = Db + offp - lop;                                        \
    _Pragma("unroll")                                                         \
    for (int k = 0; k < 8; ++k)                                               \
      if (k >= klop && k <= khip) CARR[k] = Dr[(k << 6) + lane + 1];          \
  }

#define STEP(dd_, RP2, RP1, ROUT, CARR)                                       \
  {                                                                           \
    const int dd  = (dd_);                                                    \
    const int lo  = (dd <= T + 1) ? 1 : dd - T;                               \
    const int hi  = (dd - 1 < T) ? dd - 1 : T;                                \
    const int klo = (lo - 1) >> 6;                                            \
    const int khi = (hi - 1) >> 6;                                            \
    const int krot = (klo > 0) ? klo - 1 : 0;                                 \
    float rot1[8], rot2[8];                                                   \
    _Pragma("unroll")                                                         \
    for (int k = 0; k < 8; ++k)                                               \
      if (k >= krot && k <= khi) {                                            \
        rot1[k] = ROTL1(RP1[k]);                                              \
        rot2[k] = ROTL1(RP2[k]);                                              \
      }                                                                       \
    const float dzero = (dd == 2) ? 0.0f : BIGF;                              \
    _Pragma("unroll")                                                         \
    for (int k = 0; k < 8; ++k)                                               \
      if (k >= klo && k <= khi) {                                             \
        const int i = (k << 6) + lane + 1;                                    \
        float up, dg;                                                         \
        if (k == 0) {                                                         \
          up = (lane == 0) ? BIGF : rot1[0];                                  \
          dg = (lane == 0) ? dzero : rot2[0];                                 \
        } else {                                                              \
          up = (lane == 0) ? rot1[k - 1] : rot1[k];                           \
          dg = (lane == 0) ? rot2[k - 1] : rot2[k];                           \
        }                                                                     \
        const float lf = RP1[k];                                              \
        const float mn = fminf(fminf(up, lf), dg);                            \
        const float md = __builtin_amdgcn_fmed3f(up, lf, dg);                 \
        const float mx = fmaxf(fmaxf(up, lf), dg);                            \
        const float s  = 1.0f + EXP2F(mn - md) + EXP2F(mn - mx);              \
        const float val = CARR[k] + mn - LOG2F(s);                            \
        const unsigned ju = (unsigned)(dd - i - 1);                           \
        ROUT[k] = (ju < (unsigned)T) ? val : BIGF;                            \
      }                                                                       \
    LOADDIAG(CARR, dd + 6)                                                    \
  }

__global__ __launch_bounds__(64, 1) void dp_diag_kernel(const float* __restrict__ D,
                                                        float* __restrict__ out) {
  const int b = blockIdx.x;
  const int lane = threadIdx.x;
  const float* __restrict__ Db = D + (size_t)b * (T * T);
#if !__has_builtin(__builtin_amdgcn_update_dpp)
  const int rot_addr = ((lane + 63) & 63) << 2;
#endif

  float A[8], Bv[8], C[8];
  float cA[8], cB[8], cC[8], cD[8], cE[8], cF[8];
  #pragma unroll
  for (int k = 0; k < 8; ++k) {
    A[k] = BIGF; Bv[k] = BIGF; C[k] = BIGF;
    cA[k] = 0.f; cB[k] = 0.f; cC[k] = 0.f;
    cD[k] = 0.f; cE[k] = 0.f; cF[k] = 0.f;
  }

  LOADDIAG(cA, 2)
  LOADDIAG(cB, 3)
  LOADDIAG(cC, 4)
  LOADDIAG(cD, 5)
  LOADDIAG(cE, 6)
  LOADDIAG(cF, 7)

  // A = diag 0 (all BIG; R[0][0]=0 via the k==0/lane==0 override), Bv = diag 1.
  // Main loop: 170 iters x 6 diagonals = 2..1021; tail covers 1022..1024.
  #pragma unroll 1
  for (int d0 = 2; d0 + 5 <= 2 * T; d0 += 6) {
    STEP(d0 + 0, A,  Bv, C,  cA)
    STEP(d0 + 1, Bv, C,  A,  cB)
    STEP(d0 + 2, C,  A,  Bv, cC)
    STEP(d0 + 3, A,  Bv, C,  cD)
    STEP(d0 + 4, Bv, C,  A,  cE)
    STEP(d0 + 5, C,  A,  Bv, cF)
  }
  STEP(2 * T - 2, A,  Bv, C,  cA)
  STEP(2 * T - 1, Bv, C,  A,  cB)
  STEP(2 * T,     C,  A,  Bv, cC)

  // diag 1024 landed in Bv; R'(512,512) = slot 7, lane 63.  Unscale by ln2.
  if (lane == 63) atomicAdd(out, Bv[7] * (LN2f / BATCH));
}

// ---------------------------------------------------------------------------
// Fallback (ws too small): fused on-the-fly DP (round-2 version, known good).
// ---------------------------------------------------------------------------
__global__ __launch_bounds__(512) void dp_onfly_kernel(
    const float* __restrict__ x, const float* __restrict__ y,
    float* __restrict__ out) {
  int b = blockIdx.x;
  int tid = threadIdx.x;
  int i = tid + 1;

  __shared__ float ys[T][DIMS + 1];
  __shared__ float y2s[T];
  __shared__ float rbuf[3][T + 1];

  const float* yb = y + (size_t)b * T * DIMS;
  for (int e = tid; e < T * DIMS; e += 512) {
    int r = e >> 6, c = e & 63;
    ys[r][c] = yb[e];
  }
  for (int e = tid; e < 3 * (T + 1); e += 512) ((float*)rbuf)[e] = BIGF;
  __syncthreads();
  if (tid == 0) rbuf[0][0] = 0.f;
  {
    float s = 0.f;
    #pragma unroll
    for (int k = 0; k < DIMS; ++k) { float v = ys[tid][k]; s += v * v; }
    y2s[tid] = s;
  }

  float xr[DIMS];
  float x2 = 0.f;
  const float* xb = x + ((size_t)b * T + (i - 1)) * DIMS;
  #pragma unroll
  for (int k = 0; k < DIMS; ++k) { xr[k] = xb[k]; x2 += xr[k] * xr[k]; }
  __syncthreads();

  float* rp2 = rbuf[0];
  float* rp1 = rbuf[1];
  float* rc  = rbuf[2];

  float val = BIGF;
  for (int d = 2; d <= 2 * T; ++d) {
    int j = d - i;
    bool valid = (j >= 1) && (j <= T);
    float cost = 0.f;
    if (valid) {
      float dot = 0.f;
      #pragma unroll
      for (int k = 0; k < DIMS; ++k) dot += xr[k] * ys[j - 1][k];
      cost = x2 + y2s[j - 1] - 2.f * dot;
    }
    float a = rp1[i - 1];
    float bb = rp1[i];
    float c = rp2[i - 1];
    float m = fminf(fminf(a, bb), c);
    float s = __expf(m - a) + __expf(m - bb) + __expf(m - c);
    val = valid ? (cost + m - __logf(s)) : BIGF;
    rc[i] = val;
    if (tid == 0) rc[0] = BIGF;
    __syncthreads();
    float* tmp = rp2; rp2 = rp1; rp1 = rc; rc = tmp;
  }

  if (tid == T - 1) atomicAdd(out, val * (1.0f / BATCH));
}

extern "C" void kernel_launch(void* const* d_in, const int* in_sizes, int n_in,
                              void* d_out, int out_size, void* d_ws, size_t ws_size,
                              hipStream_t stream) {
  const float* x = (const float*)d_in[0];   // inputs  (B,T,D)
  const float* y = (const float*)d_in[1];   // targets (B,T,D)
  float* out = (float*)d_out;

  hipMemsetAsync(d_out, 0, sizeof(float), stream);

  size_t needD = (size_t)BATCH * T * T * sizeof(float);  // 64 MiB
  if (ws_size >= needD) {
    float* Dw = (float*)d_ws;
    pairdist_diag_kernel<<<BATCH * 64, 256, 0, stream>>>(x, y, Dw);
    dp_diag_kernel<<<BATCH, 64, 0, stream>>>(Dw, out);
  } else {
    dp_onfly_kernel<<<BATCH, 512, 0, stream>>>(x, y, out);
  }
}

// Round 5
// 579.712 us; speedup vs baseline: 1.4822x; 1.2838x over previous
//
#include <hip/hip_runtime.h>

#define BIGF 100000000.0f
#define LOG2E 1.4426950408889634f
#define LN2f 0.6931471805599453f
constexpr int BATCH = 64;
constexpr int T = 512;     // N == M == 512
constexpr int DIMS = 64;

#if __has_builtin(__builtin_amdgcn_exp2f)
#define EXP2F(x) __builtin_amdgcn_exp2f(x)
#else
#define EXP2F(x) __expf((x) * LN2f)
#endif
#if __has_builtin(__builtin_amdgcn_logf)
#define LOG2F(x) __builtin_amdgcn_logf(x)
#else
#define LOG2F(x) (__logf(x) * LOG2E)
#endif

// lane l <- lane l-1, lane 0 <- lane 63 (full-wave rotate right by 1).
// DPP ctrl 0x13C = wave_ror:1. VALU-speed cross-lane.
#if __has_builtin(__builtin_amdgcn_update_dpp)
#define ROTL1(x) __int_as_float(__builtin_amdgcn_update_dpp(               \
    0, __float_as_int(x), 0x13C, 0xF, 0xF, 1))
#else
#define ROTL1(x) __int_as_float(__builtin_amdgcn_ds_bpermute(              \
    rot_addr, __float_as_int(x)))
#endif

// ---------------------------------------------------------------------------
// Kernel A: pairwise squared distances, written DIAGONAL-PACKED, pre-scaled
// by log2(e).  Diagonal d (d = i + j, i,j in [1,T]):
//   d <= T+1: lo = 1,   off = (d-2)(d-1)/2
//   else:     lo = d-T, off = T*T - (2T+1-d)(2T+2-d)/2
// Cell (i, d-i) stored at off + (i - lo).  Total exactly T*T floats.
// ---------------------------------------------------------------------------
__global__ __launch_bounds__(256) void pairdist_diag_kernel(
    const float* __restrict__ x, const float* __restrict__ y,
    float* __restrict__ D) {
  int bid = blockIdx.x;
  int b = bid >> 6;          // 64 tiles per batch
  int tile = bid & 63;
  int n0 = (tile >> 3) << 6; // row tile origin
  int m0 = (tile & 7) << 6;  // col tile origin

  __shared__ float xs[64][65];
  __shared__ float ys[64][65];
  __shared__ float stage[64][66];  // diag read addr = 65r + t -> bank (r+t)&31, conflict-free
  __shared__ float x2s[64], y2s[64];

  const float* xb = x + ((size_t)b * T + n0) * DIMS;
  const float* yb = y + ((size_t)b * T + m0) * DIMS;
  int tid = threadIdx.x;

  for (int e = tid; e < 64 * 64; e += 256) {
    int r = e >> 6, c = e & 63;
    xs[r][c] = xb[(size_t)r * DIMS + c];
    ys[r][c] = yb[(size_t)r * DIMS + c];
  }
  __syncthreads();

  if (tid < 64) {
    float s = 0.f;
    #pragma unroll
    for (int k = 0; k < 64; ++k) { float v = xs[tid][k]; s += v * v; }
    x2s[tid] = s;
  } else if (tid < 128) {
    int r = tid - 64;
    float s = 0.f;
    #pragma unroll
    for (int k = 0; k < 64; ++k) { float v = ys[r][k]; s += v * v; }
    y2s[r] = s;
  }
  __syncthreads();

  int tr = tid >> 4, tc = tid & 15;
  int r0 = tr * 4, c0 = tc * 4;
  float acc[4][4] = {};
  #pragma unroll 8
  for (int k = 0; k < 64; ++k) {
    float a0 = xs[r0 + 0][k], a1 = xs[r0 + 1][k];
    float a2 = xs[r0 + 2][k], a3 = xs[r0 + 3][k];
    float b0 = ys[c0 + 0][k], b1 = ys[c0 + 1][k];
    float b2 = ys[c0 + 2][k], b3 = ys[c0 + 3][k];
    acc[0][0] += a0 * b0; acc[0][1] += a0 * b1; acc[0][2] += a0 * b2; acc[0][3] += a0 * b3;
    acc[1][0] += a1 * b0; acc[1][1] += a1 * b1; acc[1][2] += a1 * b2; acc[1][3] += a1 * b3;
    acc[2][0] += a2 * b0; acc[2][1] += a2 * b1; acc[2][2] += a2 * b2; acc[2][3] += a2 * b3;
    acc[3][0] += a3 * b0; acc[3][1] += a3 * b1; acc[3][2] += a3 * b2; acc[3][3] += a3 * b3;
  }

  #pragma unroll
  for (int r = 0; r < 4; ++r) {
    float xn = x2s[r0 + r];
    #pragma unroll
    for (int c = 0; c < 4; ++c)
      stage[r0 + r][c0 + c] = (xn + y2s[c0 + c] - 2.f * acc[r][c]) * LOG2E;
  }
  __syncthreads();

  // packed writeout: wave `sub` handles tile-diagonal t = sub + 4j.
  float* Dp = D + (size_t)b * (T * T);
  int p = tid & 63;
  int sub = __builtin_amdgcn_readfirstlane(tid >> 6);
  int ldsoff = 65 * p;
  #pragma unroll 1
  for (int t = sub; t <= 126; t += 4) {
    int rlo = (t > 63) ? t - 63 : 0;
    int rhi = (t < 63) ? t : 63;
    int d = n0 + m0 + t + 2;
    int lo = (d <= T + 1) ? 1 : d - T;
    int off = (d <= T + 1) ? (((d - 2) * (d - 1)) >> 1)
                           : (T * T - (((2 * T + 1 - d) * (2 * T + 2 - d)) >> 1));
    int r = rlo + p;
    if (r <= rhi) {
      float v = ((const float*)stage)[ldsoff + 65 * rlo + t];  // stage[r][t-r]
      Dp[off + (n0 + r + 1 - lo)] = v;
    }
  }
}

// ---------------------------------------------------------------------------
// Kernel B: single-wave register DP.  Lane l owns rows i = 64k + l + 1
// (k = 0..7).  3 cyclic diagonal registers, DPP wave_ror:1 neighbor, 6-deep
// cost prefetch.  KEY CHANGE vs r4: cost loads are UNCONDITIONAL (8 per
// STEP, clamped scalar base, SGPR base + 4*lane voffset + 256k imm) so the
// waitcnt pass sees a static in-flight count and emits counted vmcnt instead
// of draining vmcnt(0) every STEP.  Inactive-slot loads are garbage but never
// consumed (same klo/khi guards).
// ---------------------------------------------------------------------------
#define LOADDIAG_U(CARR, dp_)                                                 \
  {                                                                           \
    const int dpv  = (dp_);                                                   \
    const int lop  = (dpv <= T + 1) ? 1 : dpv - T;                            \
    const int offp = (dpv <= T + 1)                                           \
        ? (((dpv - 2) * (dpv - 1)) >> 1)                                      \
        : (T * T - (((2 * T + 1 - dpv) * (2 * T + 2 - dpv)) >> 1));           \
    int g = offp - lop + 1;                                                   \
    g = (g < 0) ? 0 : g;                                                      \
    g = (g > T * T - 513) ? (T * T - 513) : g;                                \
    const float* Dg = Db + g;                                                 \
    _Pragma("unroll")                                                         \
    for (int k = 0; k < 8; ++k) CARR[k] = Dg[(k << 6) + lane];                \
  }

#define STEP(dd_, RP2, RP1, ROUT, CARR)                                       \
  {                                                                           \
    const int dd  = (dd_);                                                    \
    const int lo  = (dd <= T + 1) ? 1 : dd - T;                               \
    const int hi  = (dd - 1 < T) ? dd - 1 : T;                                \
    const int klo = (lo - 1) >> 6;                                            \
    const int khi = (hi - 1) >> 6;                                            \
    const int krot = (klo > 0) ? klo - 1 : 0;                                 \
    float rot1[8], rot2[8];                                                   \
    _Pragma("unroll")                                                         \
    for (int k = 0; k < 8; ++k)                                               \
      if (k >= krot && k <= khi) {                                            \
        rot1[k] = ROTL1(RP1[k]);                                              \
        rot2[k] = ROTL1(RP2[k]);                                              \
      }                                                                       \
    const float dzero = (dd == 2) ? 0.0f : BIGF;                              \
    _Pragma("unroll")                                                         \
    for (int k = 0; k < 8; ++k)                                               \
      if (k >= klo && k <= khi) {                                             \
        const int i = (k << 6) + lane + 1;                                    \
        float up, dg;                                                         \
        if (k == 0) {                                                         \
          up = (lane == 0) ? BIGF : rot1[0];                                  \
          dg = (lane == 0) ? dzero : rot2[0];                                 \
        } else {                                                              \
          up = (lane == 0) ? rot1[k - 1] : rot1[k];                           \
          dg = (lane == 0) ? rot2[k - 1] : rot2[k];                           \
        }                                                                     \
        const float lf = RP1[k];                                              \
        const float mn = fminf(fminf(up, lf), dg);                            \
        const float md = __builtin_amdgcn_fmed3f(up, lf, dg);                 \
        const float mx = fmaxf(fmaxf(up, lf), dg);                            \
        const float s  = 1.0f + EXP2F(mn - md) + EXP2F(mn - mx);              \
        const float val = CARR[k] + mn - LOG2F(s);                            \
        const unsigned ju = (unsigned)(dd - i - 1);                           \
        ROUT[k] = (ju < (unsigned)T) ? val : BIGF;                            \
      }                                                                       \
    LOADDIAG_U(CARR, dd + 6)                                                  \
  }

__global__ __launch_bounds__(64, 1) void dp_diag_kernel(const float* __restrict__ D,
                                                        float* __restrict__ out) {
  const int b = blockIdx.x;
  const int lane = threadIdx.x;
  const float* __restrict__ Db = D + (size_t)b * (T * T);
#if !__has_builtin(__builtin_amdgcn_update_dpp)
  const int rot_addr = ((lane + 63) & 63) << 2;
#endif

  float A[8], Bv[8], C[8];
  float cA[8], cB[8], cC[8], cD[8], cE[8], cF[8];
  #pragma unroll
  for (int k = 0; k < 8; ++k) {
    A[k] = BIGF; Bv[k] = BIGF; C[k] = BIGF;
  }

  LOADDIAG_U(cA, 2)
  LOADDIAG_U(cB, 3)
  LOADDIAG_U(cC, 4)
  LOADDIAG_U(cD, 5)
  LOADDIAG_U(cE, 6)
  LOADDIAG_U(cF, 7)

  // A = diag 0 (all BIG; R[0][0]=0 via the k==0/lane==0 override), Bv = diag 1.
  // Main loop: 170 iters x 6 diagonals = 2..1021; tail covers 1022..1024.
  #pragma unroll 1
  for (int d0 = 2; d0 + 5 <= 2 * T; d0 += 6) {
    STEP(d0 + 0, A,  Bv, C,  cA)
    STEP(d0 + 1, Bv, C,  A,  cB)
    STEP(d0 + 2, C,  A,  Bv, cC)
    STEP(d0 + 3, A,  Bv, C,  cD)
    STEP(d0 + 4, Bv, C,  A,  cE)
    STEP(d0 + 5, C,  A,  Bv, cF)
  }
  STEP(2 * T - 2, A,  Bv, C,  cA)
  STEP(2 * T - 1, Bv, C,  A,  cB)
  STEP(2 * T,     C,  A,  Bv, cC)

  // diag 1024 landed in Bv; R'(512,512) = slot 7, lane 63.  Unscale by ln2.
  if (lane == 63) atomicAdd(out, Bv[7] * (LN2f / BATCH));
}

// ---------------------------------------------------------------------------
// Fallback (ws too small): fused on-the-fly DP (round-2 version, known good).
// ---------------------------------------------------------------------------
__global__ __launch_bounds__(512) void dp_onfly_kernel(
    const float* __restrict__ x, const float* __restrict__ y,
    float* __restrict__ out) {
  int b = blockIdx.x;
  int tid = threadIdx.x;
  int i = tid + 1;

  __shared__ float ys[T][DIMS + 1];
  __shared__ float y2s[T];
  __shared__ float rbuf[3][T + 1];

  const float* yb = y + (size_t)b * T * DIMS;
  for (int e = tid; e < T * DIMS; e += 512) {
    int r = e >> 6, c = e & 63;
    ys[r][c] = yb[e];
  }
  for (int e = tid; e < 3 * (T + 1); e += 512) ((float*)rbuf)[e] = BIGF;
  __syncthreads();
  if (tid == 0) rbuf[0][0] = 0.f;
  {
    float s = 0.f;
    #pragma unroll
    for (int k = 0; k < DIMS; ++k) { float v = ys[tid][k]; s += v * v; }
    y2s[tid] = s;
  }

  float xr[DIMS];
  float x2 = 0.f;
  const float* xb = x + ((size_t)b * T + (i - 1)) * DIMS;
  #pragma unroll
  for (int k = 0; k < DIMS; ++k) { xr[k] = xb[k]; x2 += xr[k] * xr[k]; }
  __syncthreads();

  float* rp2 = rbuf[0];
  float* rp1 = rbuf[1];
  float* rc  = rbuf[2];

  float val = BIGF;
  for (int d = 2; d <= 2 * T; ++d) {
    int j = d - i;
    bool valid = (j >= 1) && (j <= T);
    float cost = 0.f;
    if (valid) {
      float dot = 0.f;
      #pragma unroll
      for (int k = 0; k < DIMS; ++k) dot += xr[k] * ys[j - 1][k];
      cost = x2 + y2s[j - 1] - 2.f * dot;
    }
    float a = rp1[i - 1];
    float bb = rp1[i];
    float c = rp2[i - 1];
    float m = fminf(fminf(a, bb), c);
    float s = __expf(m - a) + __expf(m - bb) + __expf(m - c);
    val = valid ? (cost + m - __logf(s)) : BIGF;
    rc[i] = val;
    if (tid == 0) rc[0] = BIGF;
    __syncthreads();
    float* tmp = rp2; rp2 = rp1; rp1 = rc; rc = tmp;
  }

  if (tid == T - 1) atomicAdd(out, val * (1.0f / BATCH));
}

extern "C" void kernel_launch(void* const* d_in, const int* in_sizes, int n_in,
                              void* d_out, int out_size, void* d_ws, size_t ws_size,
                              hipStream_t stream) {
  const float* x = (const float*)d_in[0];   // inputs  (B,T,D)
  const float* y = (const float*)d_in[1];   // targets (B,T,D)
  float* out = (float*)d_out;

  hipMemsetAsync(d_out, 0, sizeof(float), stream);

  size_t needD = (size_t)BATCH * T * T * sizeof(float);  // 64 MiB
  if (ws_size >= needD) {
    float* Dw = (float*)d_ws;
    pairdist_diag_kernel<<<BATCH * 64, 256, 0, stream>>>(x, y, Dw);
    dp_diag_kernel<<<BATCH, 64, 0, stream>>>(Dw, out);
  } else {
    dp_onfly_kernel<<<BATCH, 512, 0, stream>>>(x, y, out);
  }
}

// Round 8
// 431.083 us; speedup vs baseline: 1.9932x; 1.3448x over previous
//
#include <hip/hip_runtime.h>

#define BIGF 100000000.0f
#define LOG2E 1.4426950408889634f
#define LN2f 0.6931471805599453f
constexpr int BATCH = 64;
constexpr int T = 512;     // N == M == 512
constexpr int DIMS = 64;

constexpr int SS = 12;     // diagonals per superstep (multiple of 3!)
constexpr int RING = 24;   // 2 supersteps of slots
constexpr int PADF = 512;  // guard pad before ring (negative idx reads land here)
constexpr int NSS = 86;    // ceil(1023 / 12)

#if __has_builtin(__builtin_amdgcn_exp2f)
#define EXP2F(x) __builtin_amdgcn_exp2f(x)
#else
#define EXP2F(x) __expf((x) * LN2f)
#endif
#if __has_builtin(__builtin_amdgcn_logf)
#define LOG2F(x) __builtin_amdgcn_logf(x)
#else
#define LOG2F(x) (__logf(x) * LOG2E)
#endif

// lane l <- lane l-1, lane 0 <- lane 63 (full-wave rotate right by 1).
#if __has_builtin(__builtin_amdgcn_update_dpp)
#define ROTL1(x) __int_as_float(__builtin_amdgcn_update_dpp(               \
    0, __float_as_int(x), 0x13C, 0xF, 0xF, 1))
#else
#define ROTL1(x) __int_as_float(__builtin_amdgcn_ds_bpermute(              \
    rot_addr, __float_as_int(x)))
#endif

// ---------------------------------------------------------------------------
// Kernel A: pairwise squared distances, DIAGONAL-PACKED, pre-scaled by log2e.
// Diagonal d (d = i + j, i,j in [1,T]):
//   d <= T+1: lo = 1,   off = (d-2)(d-1)/2
//   else:     lo = d-T, off = T*T - (2T+1-d)(2T+2-d)/2
// Cell (i, d-i) stored at off + (i - lo).  Total exactly T*T floats.
// ---------------------------------------------------------------------------
__global__ __launch_bounds__(256) void pairdist_diag_kernel(
    const float* __restrict__ x, const float* __restrict__ y,
    float* __restrict__ D) {
  int bid = blockIdx.x;
  int b = bid >> 6;          // 64 tiles per batch
  int tile = bid & 63;
  int n0 = (tile >> 3) << 6;
  int m0 = (tile & 7) << 6;

  __shared__ float xs[64][65];
  __shared__ float ys[64][65];
  __shared__ float stage[64][66];
  __shared__ float x2s[64], y2s[64];

  const float* xb = x + ((size_t)b * T + n0) * DIMS;
  const float* yb = y + ((size_t)b * T + m0) * DIMS;
  int tid = threadIdx.x;

  for (int e = tid; e < 64 * 64; e += 256) {
    int r = e >> 6, c = e & 63;
    xs[r][c] = xb[(size_t)r * DIMS + c];
    ys[r][c] = yb[(size_t)r * DIMS + c];
  }
  __syncthreads();

  if (tid < 64) {
    float s = 0.f;
    #pragma unroll
    for (int k = 0; k < 64; ++k) { float v = xs[tid][k]; s += v * v; }
    x2s[tid] = s;
  } else if (tid < 128) {
    int r = tid - 64;
    float s = 0.f;
    #pragma unroll
    for (int k = 0; k < 64; ++k) { float v = ys[r][k]; s += v * v; }
    y2s[r] = s;
  }
  __syncthreads();

  int tr = tid >> 4, tc = tid & 15;
  int r0 = tr * 4, c0 = tc * 4;
  float acc[4][4] = {};
  #pragma unroll 8
  for (int k = 0; k < 64; ++k) {
    float a0 = xs[r0 + 0][k], a1 = xs[r0 + 1][k];
    float a2 = xs[r0 + 2][k], a3 = xs[r0 + 3][k];
    float b0 = ys[c0 + 0][k], b1 = ys[c0 + 1][k];
    float b2 = ys[c0 + 2][k], b3 = ys[c0 + 3][k];
    acc[0][0] += a0 * b0; acc[0][1] += a0 * b1; acc[0][2] += a0 * b2; acc[0][3] += a0 * b3;
    acc[1][0] += a1 * b0; acc[1][1] += a1 * b1; acc[1][2] += a1 * b2; acc[1][3] += a1 * b3;
    acc[2][0] += a2 * b0; acc[2][1] += a2 * b1; acc[2][2] += a2 * b2; acc[2][3] += a2 * b3;
    acc[3][0] += a3 * b0; acc[3][1] += a3 * b1; acc[3][2] += a3 * b2; acc[3][3] += a3 * b3;
  }

  #pragma unroll
  for (int r = 0; r < 4; ++r) {
    float xn = x2s[r0 + r];
    #pragma unroll
    for (int c = 0; c < 4; ++c)
      stage[r0 + r][c0 + c] = (xn + y2s[c0 + c] - 2.f * acc[r][c]) * LOG2E;
  }
  __syncthreads();

  float* Dp = D + (size_t)b * (T * T);
  int p = tid & 63;
  int sub = __builtin_amdgcn_readfirstlane(tid >> 6);
  int ldsoff = 65 * p;
  #pragma unroll 1
  for (int t = sub; t <= 126; t += 4) {
    int rlo = (t > 63) ? t - 63 : 0;
    int rhi = (t < 63) ? t : 63;
    int d = n0 + m0 + t + 2;
    int lo = (d <= T + 1) ? 1 : d - T;
    int off = (d <= T + 1) ? (((d - 2) * (d - 1)) >> 1)
                           : (T * T - (((2 * T + 1 - d) * (2 * T + 2 - d)) >> 1));
    int r = rlo + p;
    if (r <= rhi) {
      float v = ((const float*)stage)[ldsoff + 65 * rlo + t];  // stage[r][t-r]
      Dp[off + (n0 + r + 1 - lo)] = v;
    }
  }
}

// ---------------------------------------------------------------------------
// Kernel B: producer/consumer DP.  Wave 0 = consumer (register DP, identical
// math to the verified r4 kernel); waves 1..4 = producers staging cost
// diagonals into a double-buffered LDS ring (12 diagonals per half).  One
// __syncthreads per superstep; producer global-load latency never touches
// the consumer's serial chain.  Consumer reads costs via ds_read, double-
// banked one diagonal ahead (lgkmcnt is compiler-counted and cheap).
// ---------------------------------------------------------------------------
#define ISSUE(BANK, slot_, dd_)                                               \
  {                                                                           \
    const int di = (dd_);                                                     \
    if (di <= 2 * T) {                                                        \
      const int lo_ = (di <= T + 1) ? 1 : di - T;                             \
      const float* sp = &lds[PADF + (slot_) * T + 1 - lo_];                   \
      _Pragma("unroll")                                                       \
      for (int k = 0; k < 8; ++k) BANK[k] = sp[(k << 6) + lane];              \
    }                                                                         \
  }

#define COMPUTE(dd_, RP2, RP1, ROUT, BANK)                                    \
  {                                                                           \
    const int d_ = (dd_);                                                     \
    if (d_ <= 2 * T) {                                                        \
      const float dzero = (d_ == 2) ? 0.0f : BIGF;                            \
      float rot1[8], rot2[8];                                                 \
      _Pragma("unroll")                                                       \
      for (int k = 0; k < 8; ++k) {                                           \
        rot1[k] = ROTL1(RP1[k]);                                              \
        rot2[k] = ROTL1(RP2[k]);                                              \
      }                                                                       \
      _Pragma("unroll")                                                       \
      for (int k = 0; k < 8; ++k) {                                           \
        const int i = (k << 6) + lane + 1;                                    \
        float up, dg;                                                         \
        if (k == 0) {                                                         \
          up = (lane == 0) ? BIGF : rot1[0];                                  \
          dg = (lane == 0) ? dzero : rot2[0];                                 \
        } else {                                                              \
          up = (lane == 0) ? rot1[k - 1] : rot1[k];                           \
          dg = (lane == 0) ? rot2[k - 1] : rot2[k];                           \
        }                                                                     \
        const float lf = RP1[k];                                              \
        const float mn = fminf(fminf(up, lf), dg);                            \
        const float md = __builtin_amdgcn_fmed3f(up, lf, dg);                 \
        const float mx = fmaxf(fmaxf(up, lf), dg);                            \
        const float sv = 1.0f + EXP2F(mn - md) + EXP2F(mn - mx);              \
        const float val = BANK[k] + mn - LOG2F(sv);                           \
        const unsigned ju = (unsigned)(d_ - i - 1);                           \
        ROUT[k] = (ju < (unsigned)T) ? val : BIGF;                            \
      }                                                                       \
    }                                                                         \
  }

#define FILLSS(ss_)                                                           \
  {                                                                           \
    const int ssv = (ss_);                                                    \
    if (ssv < NSS) {                                                          \
      const int d0n = 2 + SS * ssv;                                           \
      const int halfn = (ssv & 1) * SS;                                       \
      for (int tt = wave - 1; tt < SS; tt += 4) {                             \
        const int d = d0n + tt;                                               \
        if (d <= 2 * T) {                                                     \
          const int off = (d <= T + 1)                                        \
              ? (((d - 2) * (d - 1)) >> 1)                                    \
              : (T * T - (((2 * T + 1 - d) * (2 * T + 2 - d)) >> 1));         \
          float* dst = &lds[PADF + (halfn + tt) * T];                         \
          _Pragma("unroll")                                                   \
          for (int u = 0; u < 8; ++u) {                                       \
            int gi = off + (u << 6) + lane;                                   \
            gi = (gi > T * T - 1) ? (T * T - 1) : gi;                         \
            dst[(u << 6) + lane] = Db[gi];                                    \
          }                                                                   \
        }                                                                     \
      }                                                                       \
    }                                                                         \
  }

__global__ __launch_bounds__(320, 2) void dp_ring_kernel(const float* __restrict__ D,
                                                         float* __restrict__ out) {
  const int b = blockIdx.x;
  const int tid = threadIdx.x;
  const int wave = tid >> 6;   // 0 = consumer, 1..4 = producers
  const int lane = tid & 63;
  const float* __restrict__ Db = D + (size_t)b * (T * T);
#if !__has_builtin(__builtin_amdgcn_update_dpp)
  const int rot_addr = ((lane + 63) & 63) << 2;
#endif

  __shared__ float lds[PADF + RING * T];  // ~50 KB

  float A[8], Bv[8], C[8], pcE[8], pcO[8];
  #pragma unroll
  for (int k = 0; k < 8; ++k) { A[k] = BIGF; Bv[k] = BIGF; C[k] = BIGF; }

  if (wave > 0) FILLSS(0)
  __syncthreads();

  #pragma unroll 1
  for (int s = 0; s < NSS; ++s) {
    if (wave == 0) {
      const int d0 = 2 + SS * s;
      const int half = (s & 1) * SS;
      ISSUE(pcE, half + 0, d0 + 0)
      ISSUE(pcO, half + 1, d0 + 1)
      COMPUTE(d0 + 0,  A, Bv, C, pcE)
      ISSUE(pcE, half + 2, d0 + 2)
      COMPUTE(d0 + 1, Bv, C,  A, pcO)
      ISSUE(pcO, half + 3, d0 + 3)
      COMPUTE(d0 + 2,  C, A, Bv, pcE)
      ISSUE(pcE, half + 4, d0 + 4)
      COMPUTE(d0 + 3,  A, Bv, C, pcO)
      ISSUE(pcO, half + 5, d0 + 5)
      COMPUTE(d0 + 4, Bv, C,  A, pcE)
      ISSUE(pcE, half + 6, d0 + 6)
      COMPUTE(d0 + 5,  C, A, Bv, pcO)
      ISSUE(pcO, half + 7, d0 + 7)
      COMPUTE(d0 + 6,  A, Bv, C, pcE)
      ISSUE(pcE, half + 8, d0 + 8)
      COMPUTE(d0 + 7, Bv, C,  A, pcO)
      ISSUE(pcO, half + 9, d0 + 9)
      COMPUTE(d0 + 8,  C, A, Bv, pcE)
      ISSUE(pcE, half + 10, d0 + 10)
      COMPUTE(d0 + 9,  A, Bv, C, pcO)
      ISSUE(pcO, half + 11, d0 + 11)
      COMPUTE(d0 + 10, Bv, C,  A, pcE)
      COMPUTE(d0 + 11,  C, A, Bv, pcO)
    } else {
      FILLSS(s + 1)
    }
    __syncthreads();
  }

  // diag 1024 computed at s=85, t=2 -> ROUT = Bv; R'(512,512) = slot 7 lane 63.
  if (tid == 63) atomicAdd(out, Bv[7] * (LN2f / BATCH));
}

// ---------------------------------------------------------------------------
// Fallback (ws too small): fused on-the-fly DP (round-2 version, known good).
// ---------------------------------------------------------------------------
__global__ __launch_bounds__(512) void dp_onfly_kernel(
    const float* __restrict__ x, const float* __restrict__ y,
    float* __restrict__ out) {
  int b = blockIdx.x;
  int tid = threadIdx.x;
  int i = tid + 1;

  __shared__ float ys[T][DIMS + 1];
  __shared__ float y2s[T];
  __shared__ float rbuf[3][T + 1];

  const float* yb = y + (size_t)b * T * DIMS;
  for (int e = tid; e < T * DIMS; e += 512) {
    int r = e >> 6, c = e & 63;
    ys[r][c] = yb[e];
  }
  for (int e = tid; e < 3 * (T + 1); e += 512) ((float*)rbuf)[e] = BIGF;
  __syncthreads();
  if (tid == 0) rbuf[0][0] = 0.f;
  {
    float s = 0.f;
    #pragma unroll
    for (int k = 0; k < DIMS; ++k) { float v = ys[tid][k]; s += v * v; }
    y2s[tid] = s;
  }

  float xr[DIMS];
  float x2 = 0.f;
  const float* xb = x + ((size_t)b * T + (i - 1)) * DIMS;
  #pragma unroll
  for (int k = 0; k < DIMS; ++k) { xr[k] = xb[k]; x2 += xr[k] * xr[k]; }
  __syncthreads();

  float* rp2 = rbuf[0];
  float* rp1 = rbuf[1];
  float* rc  = rbuf[2];

  float val = BIGF;
  for (int d = 2; d <= 2 * T; ++d) {
    int j = d - i;
    bool valid = (j >= 1) && (j <= T);
    float cost = 0.f;
    if (valid) {
      float dot = 0.f;
      #pragma unroll
      for (int k = 0; k < DIMS; ++k) dot += xr[k] * ys[j - 1][k];
      cost = x2 + y2s[j - 1] - 2.f * dot;
    }
    float a = rp1[i - 1];
    float bb = rp1[i];
    float c = rp2[i - 1];
    float m = fminf(fminf(a, bb), c);
    float s = __expf(m - a) + __expf(m - bb) + __expf(m - c);
    val = valid ? (cost + m - __logf(s)) : BIGF;
    rc[i] = val;
    if (tid == 0) rc[0] = BIGF;
    __syncthreads();
    float* tmp = rp2; rp2 = rp1; rp1 = rc; rc = tmp;
  }

  if (tid == T - 1) atomicAdd(out, val * (1.0f / BATCH));
}

extern "C" void kernel_launch(void* const* d_in, const int* in_sizes, int n_in,
                              void* d_out, int out_size, void* d_ws, size_t ws_size,
                              hipStream_t stream) {
  const float* x = (const float*)d_in[0];   // inputs  (B,T,D)
  const float* y = (const float*)d_in[1];   // targets (B,T,D)
  float* out = (float*)d_out;

  hipMemsetAsync(d_out, 0, sizeof(float), stream);

  size_t needD = (size_t)BATCH * T * T * sizeof(float);  // 64 MiB
  if (ws_size >= needD) {
    float* Dw = (float*)d_ws;
    pairdist_diag_kernel<<<BATCH * 64, 256, 0, stream>>>(x, y, Dw);
    dp_ring_kernel<<<BATCH, 320, 0, stream>>>(Dw, out);
  } else {
    dp_onfly_kernel<<<BATCH, 512, 0, stream>>>(x, y, out);
  }
}